// Round 6
// baseline (3435.596 us; speedup 1.0000x reference)
//
#include <hip/hip_runtime.h>
#include <cmath>

// B=32, T=128, E=512, H=1024, 4H=4096
typedef __attribute__((ext_vector_type(8))) short short8;
typedef __attribute__((ext_vector_type(4))) float f32x4;
typedef unsigned long long u64;

__device__ inline short bf16r(float x) {
  union { float f; unsigned u; } v; v.f = x;
  unsigned r = (v.u + 0x7fff + ((v.u >> 16) & 1)) >> 16;
  return (short)r;
}
__device__ inline float bf2f(short s) {
  union { unsigned u; float f; } v; v.u = ((unsigned)(unsigned short)s) << 16;
  return v.f;
}
template <int CTRL>
__device__ inline float qb(float v) {  // quad_perm broadcast within lane-quads
  int i = __builtin_bit_cast(int, v);
  int r = __builtin_amdgcn_update_dpp(0, i, CTRL, 0xf, 0xf, true);
  return __builtin_bit_cast(float, r);
}

// ---------- small prep kernels ----------
// hx layout: [t][chunk j=u>>5][b][u&31] bf16  (129 x 32KB-of-shorts)
__global__ __launch_bounds__(256) void init2(const float* __restrict__ h0,
                                             const float* __restrict__ c0,
                                             short* __restrict__ hx0,
                                             float* __restrict__ c) {
  int idx = blockIdx.x * 256 + threadIdx.x;  // (b,u) row-major
  int b = idx >> 10, u = idx & 1023;
  hx0[(u >> 5) * 1024 + b * 32 + (u & 31)] = bf16r(h0[idx]);
  c[idx] = c0[idx];
}

__global__ __launch_bounds__(256) void finalize2(const short* __restrict__ hx128,
                                                 const float* __restrict__ c,
                                                 float* __restrict__ out) {
  int idx = blockIdx.x * 256 + threadIdx.x;  // (b,u)
  int b = idx >> 10, u = idx & 1023;
  out[idx] = bf2f(hx128[(u >> 5) * 1024 + b * 32 + (u & 31)]);
  out[32768 + idx] = c[idx];
}

__global__ __launch_bounds__(256) void zero_cnt(unsigned* __restrict__ c) {
  c[blockIdx.x * 256 + threadIdx.x] = 0u;  // 8 blocks -> 2048 u32
}

__global__ __launch_bounds__(256) void copy_h(const int* __restrict__ src,
                                              int* __restrict__ dst) {
  int i = blockIdx.x * 256 + threadIdx.x;  // 16384 ints = 64KB
  dst[i] = src[i];
}

// x (B,T,E) fp32 -> xb rows r=t*32+b, (4096,512) bf16
__global__ __launch_bounds__(256) void cast_x(const float* __restrict__ x,
                                              short* __restrict__ xb) {
  int idx = blockIdx.x * 256 + threadIdx.x;
  int e = idx & 511, t = (idx >> 9) & 127, b = idx >> 16;
  xb[(((t << 5) + b) << 9) + e] = bf16r(x[idx]);
}

// permuted biases: bp[l][n'] = b_l[(n'&3)*1024 + (n'>>2)]
__global__ __launch_bounds__(256) void bias_perm(const float* __restrict__ b1,
                                                 const float* __restrict__ b2,
                                                 const float* __restrict__ b3,
                                                 const float* __restrict__ b4,
                                                 float* __restrict__ bp) {
  int idx = blockIdx.x * 256 + threadIdx.x;  // 0..16383
  int l = idx >> 12, c = idx & 4095;
  const float* s = (l == 0) ? b1 : (l == 1) ? b2 : (l == 2) ? b3 : b4;
  bp[idx] = s[((c & 3) << 10) | (c >> 2)];
}

// in fp32 (R,C) -> out bf16 (C,R); GPERM: out-row n' = (c&1023)*4 + (c>>10)
template <bool GPERM>
__global__ __launch_bounds__(256) void transpose_cast(const float* __restrict__ in,
                                                      short* __restrict__ out,
                                                      int R, int C) {
  __shared__ float tile[32][33];
  int c0 = blockIdx.x * 32, r0 = blockIdx.y * 32;
  int x = threadIdx.x & 31, y = threadIdx.x >> 5;
#pragma unroll
  for (int i = 0; i < 4; ++i)
    tile[y + i * 8][x] = in[(size_t)(r0 + y + i * 8) * C + c0 + x];
  __syncthreads();
#pragma unroll
  for (int i = 0; i < 4; ++i) {
    int c = c0 + y + i * 8;
    int n = GPERM ? (((c & 1023) << 2) | (c >> 10)) : c;
    out[(size_t)n * R + r0 + x] = bf16r(tile[x][y + i * 8]);
  }
}

// ---------- bf16 MFMA GEMM ----------
// A (M,K) bf16 rm; Bt (N,K) bf16 rm; C = A·Bt^T + bias
// MODE 1: fp32 out xWp[t][col][b] ; MODE 2: bf16 rm + relu ; MODE 3: fp32, (B,T,E)
template <int MODE>
__global__ __launch_bounds__(256) void gemm_bf16(const short* __restrict__ A,
                                                 const short* __restrict__ Bt,
                                                 const float* __restrict__ bias,
                                                 void* __restrict__ Cout,
                                                 int M, int N, int K) {
  __shared__ short As[128 * 40];
  __shared__ short Bs[128 * 40];
  const int tid = threadIdx.x;
  const int lane = tid & 63, wave = tid >> 6;
  const int lrow = lane & 15, lk = lane >> 4;
  const int m0 = (wave >> 1) * 64, n0 = (wave & 1) * 64;
  const int r = tid & 127, half = tid >> 7;
  const int mbase = blockIdx.y * 128, nbase = blockIdx.x * 128;

  f32x4 acc[4][4] = {};

  const short* Ab = A + (size_t)(mbase + r) * K + half * 16;
  const short* Bb = Bt + (size_t)(nbase + r) * K + half * 16;
  short* AsW = As + r * 40 + half * 16;
  short* BsW = Bs + r * 40 + half * 16;

  for (int k0 = 0; k0 < K; k0 += 32) {
    short8 av0 = *(const short8*)(Ab + k0);
    short8 av1 = *(const short8*)(Ab + k0 + 8);
    short8 bv0 = *(const short8*)(Bb + k0);
    short8 bv1 = *(const short8*)(Bb + k0 + 8);
    __syncthreads();
    *(short8*)(AsW) = av0;
    *(short8*)(AsW + 8) = av1;
    *(short8*)(BsW) = bv0;
    *(short8*)(BsW + 8) = bv1;
    __syncthreads();
    short8 af[4], bfr[4];
#pragma unroll
    for (int i = 0; i < 4; ++i)
      af[i] = *(const short8*)(As + (m0 + i * 16 + lrow) * 40 + lk * 8);
#pragma unroll
    for (int i = 0; i < 4; ++i)
      bfr[i] = *(const short8*)(Bs + (n0 + i * 16 + lrow) * 40 + lk * 8);
#pragma unroll
    for (int i = 0; i < 4; ++i)
#pragma unroll
      for (int j = 0; j < 4; ++j)
        acc[i][j] = __builtin_amdgcn_mfma_f32_16x16x32_bf16(af[i], bfr[j],
                                                            acc[i][j], 0, 0, 0);
  }

#pragma unroll
  for (int i = 0; i < 4; ++i) {
    const int grow0 = mbase + m0 + i * 16 + lk * 4;
#pragma unroll
    for (int j = 0; j < 4; ++j) {
      const int gcol = nbase + n0 + j * 16 + lrow;
      const float bv = bias[gcol];
      f32x4 v = acc[i][j];
      if constexpr (MODE == 1) {
        int t = grow0 >> 5, b = grow0 & 31;
        f32x4 o;
        o[0] = v[0] + bv; o[1] = v[1] + bv; o[2] = v[2] + bv; o[3] = v[3] + bv;
        *(f32x4*)((float*)Cout + ((size_t)t * 4096 + gcol) * 32 + b) = o;
      } else if constexpr (MODE == 2) {
        short* o = (short*)Cout;
#pragma unroll
        for (int jj = 0; jj < 4; ++jj)
          o[(size_t)(grow0 + jj) * N + gcol] = bf16r(fmaxf(v[jj] + bv, 0.f));
      } else {
        float* o = (float*)Cout;
#pragma unroll
        for (int jj = 0; jj < 4; ++jj) {
          int rr = grow0 + jj;
          int orow = ((rr & 31) << 7) | (rr >> 5);
          o[(size_t)orow * N + gcol] = v[jj] + bv;
        }
      }
    }
  }
}

// ---------- persistent recurrent kernel (whole layer, 128 steps) ----------
// xWp (T,4096,32) fp32 fragment layout; Utp (4096,1024) bf16 gate-interleaved;
// hx (129,32,32,32) bf16 exchange buffers [t][chunk][b][u32];
// seq (T,32,1024) bf16 output for next GEMM; cst (32,1024) fp32.
// 32 blocks x 512 threads (8 waves, 16 cols each). Block owns unit-chunk
// j=blockIdx (units j*32..+31) -> contiguous 2KB h-chunk per step.
// Staging: linear global_load_lds; A-reads conflict-free by construction.
#define PBLK 32
__global__ __launch_bounds__(512, 2) void lstm_persist(
    const float* __restrict__ xWp, const short* __restrict__ Utp,
    short* __restrict__ hx, float* __restrict__ cst, short* __restrict__ seq,
    unsigned* __restrict__ arr, int ebase) {
  __shared__ short Hs[32768];  // 64KB: [chunk j][b][u32]
  const int tid = threadIdx.x;
  const int lane = tid & 63, wave = tid >> 6;
  const int lrow = lane & 15, lk = lane >> 4;
  const int colg = blockIdx.x * 128 + wave * 16 + lrow;  // gate-interleaved n'
  const int u = colg >> 2;
  const int u0w = blockIdx.x * 32 + wave * 4;  // first unit of this wave

  // U fragment -> registers (128 VGPR, fully static)
  short8 ureg[32];
  {
    const short* Ub = Utp + (size_t)colg * 1024 + lk * 8;
#pragma unroll
    for (int j = 0; j < 32; ++j) ureg[j] = *(const short8*)(Ub + j * 32);
  }

  float creg[2][4];
#pragma unroll
  for (int h2 = 0; h2 < 2; ++h2)
#pragma unroll
    for (int jj = 0; jj < 4; ++jj)
      creg[h2][jj] = cst[(h2 * 16 + lk * 4 + jj) * 1024 + u];

  f32x4 cur0, cur1;
  {
    const float* xb = xWp + (size_t)colg * 32;
    cur0 = *(const f32x4*)(xb + lk * 4);
    cur1 = *(const f32x4*)(xb + 16 + lk * 4);
  }

  for (int t = 0; t < 128; ++t) {
    // stage h_t into LDS: fully linear (64KB, 8 waves x 8 x 1KB)
    {
      const char* src =
          (const char*)(hx + (size_t)t * 32768) + wave * 8192 + lane * 16;
      char* dstb = (char*)Hs + wave * 8192;
#pragma unroll
      for (int j = 0; j < 8; ++j)
        __builtin_amdgcn_global_load_lds(
            (const __attribute__((address_space(1))) void*)(src + j * 1024),
            (__attribute__((address_space(3))) void*)(dstb + j * 1024), 16, 0,
            0);
    }
    f32x4 acc0 = cur0, acc1 = cur1;
    __syncthreads();  // staging complete (vmcnt+lgkm drained)

    // prefetch next step's xW during MFMA phase (off the post-barrier path)
    {
      const int tn = t < 127 ? t + 1 : t;
      const float* xb = xWp + ((size_t)tn * 4096 + colg) * 32;
      cur0 = *(const f32x4*)(xb + lk * 4);
      cur1 = *(const f32x4*)(xb + 16 + lk * 4);
    }

    // MFMA: k-chunk j lives at Hs[j*2048B]; lane reads (b=lrow | lrow+16, lk)
    const char* HsB = (const char*)Hs;
#pragma unroll
    for (int j = 0; j < 32; ++j) {
      short8 a0 = *(const short8*)(HsB + j * 2048 + lrow * 64 + lk * 16);
      short8 a1 = *(const short8*)(HsB + j * 2048 + 1024 + lrow * 64 + lk * 16);
      acc0 = __builtin_amdgcn_mfma_f32_16x16x32_bf16(a0, ureg[j], acc0, 0, 0, 0);
      acc1 = __builtin_amdgcn_mfma_f32_16x16x32_bf16(a1, ureg[j], acc1, 0, 0, 0);
    }

    // gates via DPP quad broadcast (all quad lanes compute their unit)
    unsigned short hv[2][4];
#pragma unroll
    for (int h2 = 0; h2 < 2; ++h2) {
#pragma unroll
      for (int jj = 0; jj < 4; ++jj) {
        float v = h2 ? acc1[jj] : acc0[jj];
        float zi = qb<0x00>(v);
        float zf = qb<0x55>(v);
        float zg = qb<0xAA>(v);
        float zo = qb<0xFF>(v);
        float gi = 1.f / (1.f + __expf(-zi));
        float gf = 1.f / (1.f + __expf(-zf));
        float gg = fmaxf(zg, 0.f);
        float go = 1.f / (1.f + __expf(-zo));
        float cn = gf * creg[h2][jj] + gi * gg;
        creg[h2][jj] = cn;
        hv[h2][jj] = (unsigned short)bf16r(go * fmaxf(cn, 0.f));
      }
    }

    // pack 4 units -> u64; store to hx[t+1] (coherent) and seq (normal)
    char* hnxb = (char*)(hx + (size_t)(t + 1) * 32768) + blockIdx.x * 2048;
#pragma unroll
    for (int h2 = 0; h2 < 2; ++h2) {
#pragma unroll
      for (int jj = 0; jj < 4; ++jj) {
        int vv = hv[h2][jj];
        int w0 = __shfl(vv, (lane & 48) | 0, 64);
        int w1 = __shfl(vv, (lane & 48) | 4, 64);
        int w2 = __shfl(vv, (lane & 48) | 8, 64);
        int w3 = __shfl(vv, (lane & 48) | 12, 64);
        if (lrow == 0) {
          u64 pk = (u64)(unsigned)((w0 & 0xffff) | (w1 << 16)) |
                   ((u64)(unsigned)((w2 & 0xffff) | (w3 << 16)) << 32);
          int b = h2 * 16 + lk * 4 + jj;
          __hip_atomic_store((u64*)(hnxb + b * 64 + wave * 8), pk,
                             __ATOMIC_RELAXED, __HIP_MEMORY_SCOPE_AGENT);
          *(u64*)(seq + ((size_t)(t * 32 + b) * 1024 + u0w)) = pk;
        }
      }
    }

    if (t != 127) {
      __syncthreads();  // all waves' h stores drained (vmcnt(0) before barrier)
      const unsigned ep = (unsigned)(ebase + t + 1);
      if (tid == 0)
        __hip_atomic_store(arr + (blockIdx.x << 6), ep, __ATOMIC_RELAXED,
                           __HIP_MEMORY_SCOPE_AGENT);
      if (tid < PBLK) {
        while (__hip_atomic_load(arr + (tid << 6), __ATOMIC_RELAXED,
                                 __HIP_MEMORY_SCOPE_AGENT) < ep) {
        }
      }
      __syncthreads();
    }
  }

  if ((lrow & 3) == 0) {
#pragma unroll
    for (int h2 = 0; h2 < 2; ++h2)
#pragma unroll
      for (int jj = 0; jj < 4; ++jj)
        cst[(h2 * 16 + lk * 4 + jj) * 1024 + u] = creg[h2][jj];
  }
}

// ---------- launch ----------
extern "C" void kernel_launch(void* const* d_in, const int* in_sizes, int n_in,
                              void* d_out, int out_size, void* d_ws, size_t ws_size,
                              hipStream_t stream) {
  const float* x = (const float*)d_in[0];
  const float* h0 = (const float*)d_in[1];
  const float* c0 = (const float*)d_in[2];
  const float* W[4] = {(const float*)d_in[3], (const float*)d_in[6],
                       (const float*)d_in[9], (const float*)d_in[12]};
  const float* U[4] = {(const float*)d_in[4], (const float*)d_in[7],
                       (const float*)d_in[10], (const float*)d_in[13]};
  const float* bv[4] = {(const float*)d_in[5], (const float*)d_in[8],
                        (const float*)d_in[11], (const float*)d_in[14]};
  const float* Wd1 = (const float*)d_in[15];
  const float* bd1 = (const float*)d_in[16];
  const float* Wd2 = (const float*)d_in[17];
  const float* bd2 = (const float*)d_in[18];
  float* out = (float*)d_out;

  float* ws = (float*)d_ws;
  float* xWp = ws;                               // 16,777,216 f
  short* seq = (short*)(ws + 16777216);          // 4,194,304 bf16
  short* Utp = (short*)(ws + 18874368);          // 4,194,304 bf16
  short* Wtp = (short*)(ws + 20971520);          // 4,194,304 bf16
  short* xb = (short*)(ws + 23068672);           // 2,097,152 bf16
  short* hx = (short*)(ws + 24117248);           // 129*32768 bf16
  float* cst = ws + 26230784;                    // 32,768 f
  float* bp = ws + 26263552;                     // 16,384 f
  unsigned* arr = (unsigned*)(ws + 26279936);    // 2,048 u32 epoch slots
  short* D1 = (short*)xWp;                       // alias: xWp dead by dense head

  zero_cnt<<<8, 256, 0, stream>>>(arr);
  init2<<<128, 256, 0, stream>>>(h0, c0, hx, cst);
  cast_x<<<8192, 256, 0, stream>>>(x, xb);
  bias_perm<<<64, 256, 0, stream>>>(bv[0], bv[1], bv[2], bv[3], bp);

  for (int l = 0; l < 4; ++l) {
    const int K = (l == 0) ? 512 : 1024;
    transpose_cast<true><<<dim3(128, 32), 256, 0, stream>>>(U[l], Utp, 1024, 4096);
    transpose_cast<true><<<dim3(128, K / 32), 256, 0, stream>>>(W[l], Wtp, K, 4096);
    const short* A = (l == 0) ? xb : seq;
    gemm_bf16<1><<<dim3(32, 32), 256, 0, stream>>>(A, Wtp, bp + l * 4096, xWp,
                                                   4096, 4096, K);
    if (l) copy_h<<<64, 256, 0, stream>>>((const int*)(hx + 128 * 32768),
                                          (int*)hx);
    lstm_persist<<<PBLK, 512, 0, stream>>>(xWp, Utp, hx, cst, seq, arr, l * 128);
  }

  // dense head
  transpose_cast<false><<<dim3(32, 32), 256, 0, stream>>>(Wd1, Wtp, 1024, 1024);
  gemm_bf16<2><<<dim3(8, 32), 256, 0, stream>>>(seq, Wtp, bd1, D1, 4096, 1024,
                                                1024);
  transpose_cast<false><<<dim3(16, 32), 256, 0, stream>>>(Wd2, Wtp, 1024, 512);
  gemm_bf16<3><<<dim3(4, 32), 256, 0, stream>>>(D1, Wtp, bd2, out, 4096, 512,
                                                1024);

  finalize2<<<128, 256, 0, stream>>>(hx + 128 * 32768, cst, out + 2097152);
}

// Round 7
// 2356.009 us; speedup vs baseline: 1.4582x; 1.4582x over previous
//
#include <hip/hip_runtime.h>
#include <cmath>

// B=32, T=128, E=512, H=1024, 4H=4096
typedef __attribute__((ext_vector_type(8))) short short8;
typedef __attribute__((ext_vector_type(4))) float f32x4;
typedef unsigned long long u64;

__device__ inline short bf16r(float x) {
  union { float f; unsigned u; } v; v.f = x;
  unsigned r = (v.u + 0x7fff + ((v.u >> 16) & 1)) >> 16;
  return (short)r;
}
__device__ inline float bf2f(short s) {
  union { unsigned u; float f; } v; v.u = ((unsigned)(unsigned short)s) << 16;
  return v.f;
}
template <int CTRL>
__device__ inline float qb(float v) {  // quad_perm broadcast within lane-quads
  int i = __builtin_bit_cast(int, v);
  int r = __builtin_amdgcn_update_dpp(0, i, CTRL, 0xf, 0xf, true);
  return __builtin_bit_cast(float, r);
}

// hx layout: [t][chunk c=u>>4][b(32)][u&15] bf16 ; 129 buffers of 32768 shorts.
// ---------- small prep kernels ----------
__global__ __launch_bounds__(256) void init2(const float* __restrict__ h0,
                                             const float* __restrict__ c0,
                                             short* __restrict__ hx0,
                                             float* __restrict__ c) {
  int idx = blockIdx.x * 256 + threadIdx.x;  // (b,u) row-major
  int b = idx >> 10, u = idx & 1023;
  hx0[(u >> 4) * 512 + b * 16 + (u & 15)] = bf16r(h0[idx]);
  c[idx] = c0[idx];
}

__global__ __launch_bounds__(256) void finalize2(const short* __restrict__ hx128,
                                                 const float* __restrict__ c,
                                                 float* __restrict__ out) {
  int idx = blockIdx.x * 256 + threadIdx.x;  // (b,u)
  int b = idx >> 10, u = idx & 1023;
  out[idx] = bf2f(hx128[(u >> 4) * 512 + b * 16 + (u & 15)]);
  out[32768 + idx] = c[idx];
}

__global__ __launch_bounds__(256) void zero_cnt(unsigned* __restrict__ c) {
  c[blockIdx.x * 256 + threadIdx.x] = 0u;  // 16 blocks -> 4096 u32
}

__global__ __launch_bounds__(256) void copy_h(const int* __restrict__ src,
                                              int* __restrict__ dst) {
  int i = blockIdx.x * 256 + threadIdx.x;  // 16384 ints = 64KB
  dst[i] = src[i];
}

// x (B,T,E) fp32 -> xb rows r=t*32+b, (4096,512) bf16
__global__ __launch_bounds__(256) void cast_x(const float* __restrict__ x,
                                              short* __restrict__ xb) {
  int idx = blockIdx.x * 256 + threadIdx.x;
  int e = idx & 511, t = (idx >> 9) & 127, b = idx >> 16;
  xb[(((t << 5) + b) << 9) + e] = bf16r(x[idx]);
}

// permuted biases: bp[l][n'] = b_l[(n'&3)*1024 + (n'>>2)]
__global__ __launch_bounds__(256) void bias_perm(const float* __restrict__ b1,
                                                 const float* __restrict__ b2,
                                                 const float* __restrict__ b3,
                                                 const float* __restrict__ b4,
                                                 float* __restrict__ bp) {
  int idx = blockIdx.x * 256 + threadIdx.x;  // 0..16383
  int l = idx >> 12, c = idx & 4095;
  const float* s = (l == 0) ? b1 : (l == 1) ? b2 : (l == 2) ? b3 : b4;
  bp[idx] = s[((c & 3) << 10) | (c >> 2)];
}

// in fp32 (R,C) -> out bf16 (C,R); GPERM: out-row n' = (c&1023)*4 + (c>>10)
template <bool GPERM>
__global__ __launch_bounds__(256) void transpose_cast(const float* __restrict__ in,
                                                      short* __restrict__ out,
                                                      int R, int C) {
  __shared__ float tile[32][33];
  int c0 = blockIdx.x * 32, r0 = blockIdx.y * 32;
  int x = threadIdx.x & 31, y = threadIdx.x >> 5;
#pragma unroll
  for (int i = 0; i < 4; ++i)
    tile[y + i * 8][x] = in[(size_t)(r0 + y + i * 8) * C + c0 + x];
  __syncthreads();
#pragma unroll
  for (int i = 0; i < 4; ++i) {
    int c = c0 + y + i * 8;
    int n = GPERM ? (((c & 1023) << 2) | (c >> 10)) : c;
    out[(size_t)n * R + r0 + x] = bf16r(tile[x][y + i * 8]);
  }
}

// ---------- bf16 MFMA GEMM ----------
// A: if AHX, A points at hx-layout sequence (row r=t*32+b, k=unit); else (M,K) rm.
// Bt (N,K) bf16 rm; C = A·Bt^T + bias
// MODE 1: fp32 out xWp[t][col][b] ; MODE 2: bf16 rm + relu ; MODE 3: fp32, (B,T,E)
template <int MODE, bool AHX>
__global__ __launch_bounds__(256) void gemm_bf16(const short* __restrict__ A,
                                                 const short* __restrict__ Bt,
                                                 const float* __restrict__ bias,
                                                 void* __restrict__ Cout,
                                                 int M, int N, int K) {
  __shared__ short As[128 * 40];
  __shared__ short Bs[128 * 40];
  const int tid = threadIdx.x;
  const int lane = tid & 63, wave = tid >> 6;
  const int lrow = lane & 15, lk = lane >> 4;
  const int m0 = (wave >> 1) * 64, n0 = (wave & 1) * 64;
  const int r = tid & 127, half = tid >> 7;
  const int mbase = blockIdx.y * 128, nbase = blockIdx.x * 128;

  f32x4 acc[4][4] = {};

  const short* Ab = A + (size_t)(mbase + r) * K + half * 16;
  const short* Ahx =
      A + (size_t)((mbase + r) >> 5) * 32768 + half * 512 + ((mbase + r) & 31) * 16;
  const short* Bb = Bt + (size_t)(nbase + r) * K + half * 16;
  short* AsW = As + r * 40 + half * 16;
  short* BsW = Bs + r * 40 + half * 16;

  for (int k0 = 0; k0 < K; k0 += 32) {
    short8 av0, av1;
    if constexpr (AHX) {
      const short* ap = Ahx + (k0 >> 4) * 512;
      av0 = *(const short8*)ap;
      av1 = *(const short8*)(ap + 8);
    } else {
      av0 = *(const short8*)(Ab + k0);
      av1 = *(const short8*)(Ab + k0 + 8);
    }
    short8 bv0 = *(const short8*)(Bb + k0);
    short8 bv1 = *(const short8*)(Bb + k0 + 8);
    __syncthreads();
    *(short8*)(AsW) = av0;
    *(short8*)(AsW + 8) = av1;
    *(short8*)(BsW) = bv0;
    *(short8*)(BsW + 8) = bv1;
    __syncthreads();
    short8 af[4], bfr[4];
#pragma unroll
    for (int i = 0; i < 4; ++i)
      af[i] = *(const short8*)(As + (m0 + i * 16 + lrow) * 40 + lk * 8);
#pragma unroll
    for (int i = 0; i < 4; ++i)
      bfr[i] = *(const short8*)(Bs + (n0 + i * 16 + lrow) * 40 + lk * 8);
#pragma unroll
    for (int i = 0; i < 4; ++i)
#pragma unroll
      for (int j = 0; j < 4; ++j)
        acc[i][j] = __builtin_amdgcn_mfma_f32_16x16x32_bf16(af[i], bfr[j],
                                                            acc[i][j], 0, 0, 0);
  }

#pragma unroll
  for (int i = 0; i < 4; ++i) {
    const int grow0 = mbase + m0 + i * 16 + lk * 4;
#pragma unroll
    for (int j = 0; j < 4; ++j) {
      const int gcol = nbase + n0 + j * 16 + lrow;
      const float bv = bias[gcol];
      f32x4 v = acc[i][j];
      if constexpr (MODE == 1) {
        int t = grow0 >> 5, b = grow0 & 31;
        f32x4 o;
        o[0] = v[0] + bv; o[1] = v[1] + bv; o[2] = v[2] + bv; o[3] = v[3] + bv;
        *(f32x4*)((float*)Cout + ((size_t)t * 4096 + gcol) * 32 + b) = o;
      } else if constexpr (MODE == 2) {
        short* o = (short*)Cout;
#pragma unroll
        for (int jj = 0; jj < 4; ++jj)
          o[(size_t)(grow0 + jj) * N + gcol] = bf16r(fmaxf(v[jj] + bv, 0.f));
      } else {
        float* o = (float*)Cout;
#pragma unroll
        for (int jj = 0; jj < 4; ++jj) {
          int rr = grow0 + jj;
          int orow = ((rr & 31) << 7) | (rr >> 5);
          o[(size_t)orow * N + gcol] = v[jj] + bv;
        }
      }
    }
  }
}

// ---------- persistent recurrent kernel (whole layer, 128 steps) ----------
// xWp (T,4096,32) fp32 fragment layout; Utp (4096,1024) bf16 gate-interleaved;
// hx (129,32768) bf16 exchange [t][chunk][b][u16]; cst (32,1024) fp32.
// 64 blocks x 256 threads (4 waves x 16 cols). Block owns units 16*bid..+15
// (1KB contiguous store region per step). Linear gload_lds staging.
#define PBLK 64
__global__ __launch_bounds__(256) void lstm_persist(
    const float* __restrict__ xWp, const short* __restrict__ Utp,
    short* __restrict__ hx, float* __restrict__ cst,
    unsigned* __restrict__ arr, int ebase) {
  __shared__ short Hs[32768];  // 64KB: h_t in chunk layout
  const int tid = threadIdx.x;
  const int lane = tid & 63, wave = tid >> 6;
  const int lrow = lane & 15, lk = lane >> 4;
  const int bid = blockIdx.x;
  const int colg = bid * 64 + wave * 16 + lrow;  // gate-interleaved n'
  const int g = colg & 3;
  const int u = colg >> 2;

  // U fragment -> registers (128 VGPR, fully static)
  short8 ureg[32];
  {
    const short* Ub = Utp + (size_t)colg * 1024 + lk * 8;
#pragma unroll
    for (int j = 0; j < 32; ++j) ureg[j] = *(const short8*)(Ub + j * 32);
  }

  float creg[2][4];
#pragma unroll
  for (int h2 = 0; h2 < 2; ++h2)
#pragma unroll
    for (int jj = 0; jj < 4; ++jj)
      creg[h2][jj] = cst[(h2 * 16 + lk * 4 + jj) * 1024 + u];

  f32x4 cur0, cur1;
  {
    const float* xb = xWp + (size_t)colg * 32;
    cur0 = *(const f32x4*)(xb + lk * 4);
    cur1 = *(const f32x4*)(xb + 16 + lk * 4);
  }

  for (int t = 0; t < 128; ++t) {
    // stage hx[t] (64KB) linearly into LDS
    {
      const char* src = (const char*)(hx + (size_t)t * 32768) + tid * 16;
      char* dst = (char*)Hs + tid * 16;
#pragma unroll
      for (int i = 0; i < 16; ++i)
        __builtin_amdgcn_global_load_lds(
            (const __attribute__((address_space(1))) void*)(src + i * 4096),
            (__attribute__((address_space(3))) void*)(dst + i * 4096), 16, 0, 0);
    }
    f32x4 acc0 = cur0, acc1 = cur1;
    __syncthreads();  // staging complete

    // prefetch next step's xW (completes during MFMA phase)
    if (t < 127) {
      const float* xb = xWp + ((size_t)(t + 1) * 4096 + colg) * 32;
      cur0 = *(const f32x4*)(xb + lk * 4);
      cur1 = *(const f32x4*)(xb + 16 + lk * 4);
    }

    // MFMA: k-chunk pair per j; A-frag (b=lrow / lrow+16, k=j*32+lk*8..)
    const char* HsB = (const char*)Hs;
#pragma unroll
    for (int j = 0; j < 32; ++j) {
      int c0 = (2 * j + (lk >> 1)) * 1024 + lrow * 32 + (lk & 1) * 16;
      short8 a0 = *(const short8*)(HsB + c0);
      short8 a1 = *(const short8*)(HsB + c0 + 512);
      acc0 = __builtin_amdgcn_mfma_f32_16x16x32_bf16(a0, ureg[j], acc0, 0, 0, 0);
      acc1 = __builtin_amdgcn_mfma_f32_16x16x32_bf16(a1, ureg[j], acc1, 0, 0, 0);
    }

    // gates: lane activates its own gate's z, then quad-broadcasts
    unsigned short hv[2][4];
#pragma unroll
    for (int h2 = 0; h2 < 2; ++h2) {
#pragma unroll
      for (int jj = 0; jj < 4; ++jj) {
        float v = h2 ? acc1[jj] : acc0[jj];
        float sg = 1.f / (1.f + __expf(-v));
        float act = (g == 2) ? fmaxf(v, 0.f) : sg;
        float gi = qb<0x00>(act);
        float gf = qb<0x55>(act);
        float gg = qb<0xAA>(act);
        float go = qb<0xFF>(act);
        float cn = gf * creg[h2][jj] + gi * gg;
        creg[h2][jj] = cn;
        hv[h2][jj] = (unsigned short)bf16r(go * fmaxf(cn, 0.f));
      }
    }

    // pack 4 units (quad-lane 0 of each quad) -> u64; store to hx[t+1]
    char* hnxb = (char*)(hx + (size_t)(t + 1) * 32768) + bid * 1024 + wave * 8;
#pragma unroll
    for (int h2 = 0; h2 < 2; ++h2) {
#pragma unroll
      for (int jj = 0; jj < 4; ++jj) {
        int vv = hv[h2][jj];
        int w0 = __shfl(vv, (lane & 48) | 0, 64);
        int w1 = __shfl(vv, (lane & 48) | 4, 64);
        int w2 = __shfl(vv, (lane & 48) | 8, 64);
        int w3 = __shfl(vv, (lane & 48) | 12, 64);
        if (lrow == 0) {
          u64 pk = (u64)(unsigned)((w0 & 0xffff) | (w1 << 16)) |
                   ((u64)(unsigned)((w2 & 0xffff) | (w3 << 16)) << 32);
          int b = h2 * 16 + lk * 4 + jj;
          __hip_atomic_store((u64*)(hnxb + b * 32), pk, __ATOMIC_RELAXED,
                             __HIP_MEMORY_SCOPE_AGENT);
        }
      }
    }

    if (t != 127) {
      __syncthreads();  // drains h stores (vmcnt(0) before s_barrier)
      const unsigned ep = (unsigned)(ebase + t + 1);
      if (tid == 0)
        __hip_atomic_store(arr + (bid << 6), ep, __ATOMIC_RELAXED,
                           __HIP_MEMORY_SCOPE_AGENT);
      if (tid < PBLK) {
        while (__hip_atomic_load(arr + (tid << 6), __ATOMIC_RELAXED,
                                 __HIP_MEMORY_SCOPE_AGENT) < ep)
          __builtin_amdgcn_s_sleep(1);
      }
      __syncthreads();
    }
  }

  if ((lrow & 3) == 0) {
#pragma unroll
    for (int h2 = 0; h2 < 2; ++h2)
#pragma unroll
      for (int jj = 0; jj < 4; ++jj)
        cst[(h2 * 16 + lk * 4 + jj) * 1024 + u] = creg[h2][jj];
  }
}

// ---------- launch ----------
extern "C" void kernel_launch(void* const* d_in, const int* in_sizes, int n_in,
                              void* d_out, int out_size, void* d_ws, size_t ws_size,
                              hipStream_t stream) {
  const float* x = (const float*)d_in[0];
  const float* h0 = (const float*)d_in[1];
  const float* c0 = (const float*)d_in[2];
  const float* W[4] = {(const float*)d_in[3], (const float*)d_in[6],
                       (const float*)d_in[9], (const float*)d_in[12]};
  const float* U[4] = {(const float*)d_in[4], (const float*)d_in[7],
                       (const float*)d_in[10], (const float*)d_in[13]};
  const float* bv[4] = {(const float*)d_in[5], (const float*)d_in[8],
                        (const float*)d_in[11], (const float*)d_in[14]};
  const float* Wd1 = (const float*)d_in[15];
  const float* bd1 = (const float*)d_in[16];
  const float* Wd2 = (const float*)d_in[17];
  const float* bd2 = (const float*)d_in[18];
  float* out = (float*)d_out;

  float* ws = (float*)d_ws;
  float* xWp = ws;                               // 16,777,216 f (64MB)
  short* Utp = (short*)(ws + 16777216);          // 4,194,304 bf16
  short* Wtp = (short*)(ws + 18874368);          // 4,194,304 bf16
  short* xb = (short*)(ws + 20971520);           // 2,097,152 bf16
  short* hx = (short*)(ws + 22020096);           // 129*32768 bf16
  float* cst = ws + 24133632;                    // 32,768 f
  float* bp = ws + 24166400;                     // 16,384 f
  unsigned* arr = (unsigned*)(ws + 24182784);    // 4,096 u32 epoch slots
  short* D1 = (short*)xWp;                       // alias: xWp dead by dense head

  zero_cnt<<<16, 256, 0, stream>>>(arr);
  init2<<<128, 256, 0, stream>>>(h0, c0, hx, cst);
  cast_x<<<8192, 256, 0, stream>>>(x, xb);
  bias_perm<<<64, 256, 0, stream>>>(bv[0], bv[1], bv[2], bv[3], bp);

  for (int l = 0; l < 4; ++l) {
    const int K = (l == 0) ? 512 : 1024;
    transpose_cast<true><<<dim3(128, 32), 256, 0, stream>>>(U[l], Utp, 1024, 4096);
    transpose_cast<true><<<dim3(128, K / 32), 256, 0, stream>>>(W[l], Wtp, K, 4096);
    if (l == 0) {
      gemm_bf16<1, false><<<dim3(32, 32), 256, 0, stream>>>(
          xb, Wtp, bp, xWp, 4096, 4096, 512);
    } else {
      gemm_bf16<1, true><<<dim3(32, 32), 256, 0, stream>>>(
          hx + 32768, Wtp, bp + l * 4096, xWp, 4096, 4096, 1024);
      copy_h<<<64, 256, 0, stream>>>((const int*)(hx + 128 * 32768), (int*)hx);
    }
    lstm_persist<<<PBLK, 256, 0, stream>>>(xWp, Utp, hx, cst, arr, l * 128);
  }

  // dense head: A = layer-4 h sequence in hx layout
  transpose_cast<false><<<dim3(32, 32), 256, 0, stream>>>(Wd1, Wtp, 1024, 1024);
  gemm_bf16<2, true><<<dim3(8, 32), 256, 0, stream>>>(hx + 32768, Wtp, bd1, D1,
                                                      4096, 1024, 1024);
  transpose_cast<false><<<dim3(16, 32), 256, 0, stream>>>(Wd2, Wtp, 1024, 512);
  gemm_bf16<3, false><<<dim3(4, 32), 256, 0, stream>>>(D1, Wtp, bd2, out, 4096,
                                                       512, 1024);

  finalize2<<<128, 256, 0, stream>>>(hx + 128 * 32768, cst, out + 2097152);
}

// Round 8
// 2114.482 us; speedup vs baseline: 1.6248x; 1.1142x over previous
//
#include <hip/hip_runtime.h>
#include <cmath>

// B=32, T=128, E=512, H=1024, 4H=4096
typedef __attribute__((ext_vector_type(8))) short short8;
typedef __attribute__((ext_vector_type(4))) float f32x4;
typedef unsigned long long u64;

__device__ inline short bf16r(float x) {
  union { float f; unsigned u; } v; v.f = x;
  unsigned r = (v.u + 0x7fff + ((v.u >> 16) & 1)) >> 16;
  return (short)r;
}
__device__ inline float bf2f(short s) {
  union { unsigned u; float f; } v; v.u = ((unsigned)(unsigned short)s) << 16;
  return v.f;
}

// hx layout: [t][chunk c=u>>4][b(32)][u&15] bf16 ; 129 buffers of 32768 shorts.
// ---------- small prep kernels ----------
__global__ __launch_bounds__(256) void init2(const float* __restrict__ h0,
                                             const float* __restrict__ c0,
                                             short* __restrict__ hx0,
                                             float* __restrict__ c) {
  int idx = blockIdx.x * 256 + threadIdx.x;  // (b,u) row-major
  int b = idx >> 10, u = idx & 1023;
  hx0[(u >> 4) * 512 + b * 16 + (u & 15)] = bf16r(h0[idx]);
  c[idx] = c0[idx];
}

__global__ __launch_bounds__(256) void finalize2(const short* __restrict__ hx128,
                                                 const float* __restrict__ c,
                                                 float* __restrict__ out) {
  int idx = blockIdx.x * 256 + threadIdx.x;  // (b,u)
  int b = idx >> 10, u = idx & 1023;
  out[idx] = bf2f(hx128[(u >> 4) * 512 + b * 16 + (u & 15)]);
  out[32768 + idx] = c[idx];
}

__global__ __launch_bounds__(256) void zero_cnt(unsigned* __restrict__ c) {
  c[blockIdx.x * 256 + threadIdx.x] = 0u;  // 16 blocks -> 4096 u32
}

__global__ __launch_bounds__(256) void copy_h(const int* __restrict__ src,
                                              int* __restrict__ dst) {
  int i = blockIdx.x * 256 + threadIdx.x;  // 16384 ints = 64KB
  dst[i] = src[i];
}

// x (B,T,E) fp32 -> xb rows r=t*32+b, (4096,512) bf16
__global__ __launch_bounds__(256) void cast_x(const float* __restrict__ x,
                                              short* __restrict__ xb) {
  int idx = blockIdx.x * 256 + threadIdx.x;
  int e = idx & 511, t = (idx >> 9) & 127, b = idx >> 16;
  xb[(((t << 5) + b) << 9) + e] = bf16r(x[idx]);
}

// permuted biases: bp[l][n'] = b_l[(n'&3)*1024 + (n'>>2)]
__global__ __launch_bounds__(256) void bias_perm(const float* __restrict__ b1,
                                                 const float* __restrict__ b2,
                                                 const float* __restrict__ b3,
                                                 const float* __restrict__ b4,
                                                 float* __restrict__ bp) {
  int idx = blockIdx.x * 256 + threadIdx.x;  // 0..16383
  int l = idx >> 12, c = idx & 4095;
  const float* s = (l == 0) ? b1 : (l == 1) ? b2 : (l == 2) ? b3 : b4;
  bp[idx] = s[((c & 3) << 10) | (c >> 2)];
}

// in fp32 (R,C) -> out bf16 (C,R); GPERM: out-row n' = (c&1023)*4 + (c>>10)
template <bool GPERM>
__global__ __launch_bounds__(256) void transpose_cast(const float* __restrict__ in,
                                                      short* __restrict__ out,
                                                      int R, int C) {
  __shared__ float tile[32][33];
  int c0 = blockIdx.x * 32, r0 = blockIdx.y * 32;
  int x = threadIdx.x & 31, y = threadIdx.x >> 5;
#pragma unroll
  for (int i = 0; i < 4; ++i)
    tile[y + i * 8][x] = in[(size_t)(r0 + y + i * 8) * C + c0 + x];
  __syncthreads();
#pragma unroll
  for (int i = 0; i < 4; ++i) {
    int c = c0 + y + i * 8;
    int n = GPERM ? (((c & 1023) << 2) | (c >> 10)) : c;
    out[(size_t)n * R + r0 + x] = bf16r(tile[x][y + i * 8]);
  }
}

// ---------- bf16 MFMA GEMM ----------
// A: if AHX, A points at hx-layout sequence (row r=t*32+b, k=unit); else (M,K) rm.
// Bt (N,K) bf16 rm; C = A·Bt^T + bias
// MODE 1: fp32 out, row-major [r=t*32+b][col] (xWp) ; MODE 2: bf16 rm + relu ;
// MODE 3: fp32, (B,T,E)
template <int MODE, bool AHX>
__global__ __launch_bounds__(256) void gemm_bf16(const short* __restrict__ A,
                                                 const short* __restrict__ Bt,
                                                 const float* __restrict__ bias,
                                                 void* __restrict__ Cout,
                                                 int M, int N, int K) {
  __shared__ short As[128 * 40];
  __shared__ short Bs[128 * 40];
  const int tid = threadIdx.x;
  const int lane = tid & 63, wave = tid >> 6;
  const int lrow = lane & 15, lk = lane >> 4;
  const int m0 = (wave >> 1) * 64, n0 = (wave & 1) * 64;
  const int r = tid & 127, half = tid >> 7;
  const int mbase = blockIdx.y * 128, nbase = blockIdx.x * 128;

  f32x4 acc[4][4] = {};

  const short* Ab = A + (size_t)(mbase + r) * K + half * 16;
  const short* Ahx =
      A + (size_t)((mbase + r) >> 5) * 32768 + half * 512 + ((mbase + r) & 31) * 16;
  const short* Bb = Bt + (size_t)(nbase + r) * K + half * 16;
  short* AsW = As + r * 40 + half * 16;
  short* BsW = Bs + r * 40 + half * 16;

  for (int k0 = 0; k0 < K; k0 += 32) {
    short8 av0, av1;
    if constexpr (AHX) {
      const short* ap = Ahx + (k0 >> 4) * 512;
      av0 = *(const short8*)ap;
      av1 = *(const short8*)(ap + 8);
    } else {
      av0 = *(const short8*)(Ab + k0);
      av1 = *(const short8*)(Ab + k0 + 8);
    }
    short8 bv0 = *(const short8*)(Bb + k0);
    short8 bv1 = *(const short8*)(Bb + k0 + 8);
    __syncthreads();
    *(short8*)(AsW) = av0;
    *(short8*)(AsW + 8) = av1;
    *(short8*)(BsW) = bv0;
    *(short8*)(BsW + 8) = bv1;
    __syncthreads();
    short8 af[4], bfr[4];
#pragma unroll
    for (int i = 0; i < 4; ++i)
      af[i] = *(const short8*)(As + (m0 + i * 16 + lrow) * 40 + lk * 8);
#pragma unroll
    for (int i = 0; i < 4; ++i)
      bfr[i] = *(const short8*)(Bs + (n0 + i * 16 + lrow) * 40 + lk * 8);
#pragma unroll
    for (int i = 0; i < 4; ++i)
#pragma unroll
      for (int j = 0; j < 4; ++j)
        acc[i][j] = __builtin_amdgcn_mfma_f32_16x16x32_bf16(af[i], bfr[j],
                                                            acc[i][j], 0, 0, 0);
  }

#pragma unroll
  for (int i = 0; i < 4; ++i) {
    const int grow0 = mbase + m0 + i * 16 + lk * 4;
#pragma unroll
    for (int j = 0; j < 4; ++j) {
      const int gcol = nbase + n0 + j * 16 + lrow;
      const float bv = bias[gcol];
      f32x4 v = acc[i][j];
      if constexpr (MODE == 1) {
        float* o = (float*)Cout;
#pragma unroll
        for (int jj = 0; jj < 4; ++jj)
          o[(size_t)(grow0 + jj) * N + gcol] = v[jj] + bv;
      } else if constexpr (MODE == 2) {
        short* o = (short*)Cout;
#pragma unroll
        for (int jj = 0; jj < 4; ++jj)
          o[(size_t)(grow0 + jj) * N + gcol] = bf16r(fmaxf(v[jj] + bv, 0.f));
      } else {
        float* o = (float*)Cout;
#pragma unroll
        for (int jj = 0; jj < 4; ++jj) {
          int rr = grow0 + jj;
          int orow = ((rr & 31) << 7) | (rr >> 5);
          o[(size_t)orow * N + gcol] = v[jj] + bv;
        }
      }
    }
  }
}

// ---------- persistent recurrent kernel (whole layer, 128 steps) ----------
// xWp [t*32+b][col] fp32 row-major; Utp (4096,1024) bf16 gate-interleaved;
// hx (129,32768) bf16 exchange [t][chunk][b][u16]; cst (32,1024) fp32.
// 64 blocks x 256 threads. OPERAND-SWAPPED MFMA: acc = mfma(A=U, B=h) so
// lane (b=lrow, u=bid*16+wave*4+lk) holds all 4 gates in acc regs (gate=reg).
// Split-half poll/stage: detect chunks 32..63 while staging 0..31.
#define PBLK 64
__global__ __launch_bounds__(256) void lstm_persist(
    const float* __restrict__ xWp, const short* __restrict__ Utp,
    short* __restrict__ hx, float* __restrict__ cst,
    unsigned* __restrict__ arr, int ebase) {
  __shared__ short Hs[32768];  // 64KB: h_t in chunk layout
  const int tid = threadIdx.x;
  const int lane = tid & 63, wave = tid >> 6;
  const int lrow = lane & 15, lk = lane >> 4;
  const int bid = blockIdx.x;
  const int ucol = bid * 64 + wave * 16 + lrow;    // A-operand row (U col)
  const int col4 = bid * 64 + wave * 16 + lk * 4;  // first z-col of this lane
  const int u = bid * 16 + wave * 4 + lk;          // unit owned by this lane

  // U fragment -> registers (A-operand; same per-lane reads as before)
  short8 ureg[32];
  {
    const short* Ub = Utp + (size_t)ucol * 1024 + lk * 8;
#pragma unroll
    for (int j = 0; j < 32; ++j) ureg[j] = *(const short8*)(Ub + j * 32);
  }

  float creg0 = cst[lrow * 1024 + u];
  float creg1 = cst[(lrow + 16) * 1024 + u];

  f32x4 cur0, cur1;
  {
    cur0 = *(const f32x4*)(xWp + (size_t)lrow * 4096 + col4);
    cur1 = *(const f32x4*)(xWp + (size_t)(lrow + 16) * 4096 + col4);
  }

  for (int t = 0; t < 128; ++t) {
    const unsigned ep = (unsigned)(ebase + t);
    const char* src = (const char*)(hx + (size_t)t * 32768) + tid * 16;
    char* dst = (char*)Hs + tid * 16;

    if (t) {
      // poll first half (chunks 0..31)
      if (tid < 32)
        while (__hip_atomic_load(arr + (tid << 6), __ATOMIC_RELAXED,
                                 __HIP_MEMORY_SCOPE_AGENT) < ep)
          __builtin_amdgcn_s_sleep(1);
      __syncthreads();  // also fences prior iter's LDS reads (WAR)
    }
#pragma unroll
    for (int i = 0; i < 8; ++i)
      __builtin_amdgcn_global_load_lds(
          (const __attribute__((address_space(1))) void*)(src + i * 4096),
          (__attribute__((address_space(3))) void*)(dst + i * 4096), 16, 0, 0);
    if (t) {
      // poll second half while first half's loads are in flight
      if (tid < 32)
        while (__hip_atomic_load(arr + ((32 + tid) << 6), __ATOMIC_RELAXED,
                                 __HIP_MEMORY_SCOPE_AGENT) < ep)
          __builtin_amdgcn_s_sleep(1);
      __syncthreads();
    }
#pragma unroll
    for (int i = 8; i < 16; ++i)
      __builtin_amdgcn_global_load_lds(
          (const __attribute__((address_space(1))) void*)(src + i * 4096),
          (__attribute__((address_space(3))) void*)(dst + i * 4096), 16, 0, 0);
    __syncthreads();  // staging complete

    f32x4 acc0 = cur0, acc1 = cur1;

    // prefetch next step's xW (completes during MFMA/gates)
    if (t < 127) {
      const float* xb = xWp + ((size_t)(t + 1) * 32) * 4096 + col4;
      cur0 = *(const f32x4*)(xb + (size_t)lrow * 4096);
      cur1 = *(const f32x4*)(xb + (size_t)(lrow + 16) * 4096);
    }

    // MFMA (swapped): acc = U-frag x h-frag ; h reads identical to before
    const char* HsB = (const char*)Hs;
#pragma unroll
    for (int j = 0; j < 32; ++j) {
      int c0 = (2 * j + (lk >> 1)) * 1024 + lrow * 32 + (lk & 1) * 16;
      short8 b0 = *(const short8*)(HsB + c0);
      short8 b1 = *(const short8*)(HsB + c0 + 512);
      acc0 = __builtin_amdgcn_mfma_f32_16x16x32_bf16(ureg[j], b0, acc0, 0, 0, 0);
      acc1 = __builtin_amdgcn_mfma_f32_16x16x32_bf16(ureg[j], b1, acc1, 0, 0, 0);
    }

    // gates: all 4 in-lane (gate = reg index), no cross-lane ops
    int p0, p1;
    {
      float gi = 1.f / (1.f + __expf(-acc0[0]));
      float gf = 1.f / (1.f + __expf(-acc0[1]));
      float gg = fmaxf(acc0[2], 0.f);
      float go = 1.f / (1.f + __expf(-acc0[3]));
      float cn = gf * creg0 + gi * gg;
      creg0 = cn;
      p0 = (int)(unsigned short)bf16r(go * fmaxf(cn, 0.f));
    }
    {
      float gi = 1.f / (1.f + __expf(-acc1[0]));
      float gf = 1.f / (1.f + __expf(-acc1[1]));
      float gg = fmaxf(acc1[2], 0.f);
      float go = 1.f / (1.f + __expf(-acc1[3]));
      float cn = gf * creg1 + gi * gg;
      creg1 = cn;
      p1 = (int)(unsigned short)bf16r(go * fmaxf(cn, 0.f));
    }

    // pack: u64 = 4 units (lk 0..3) of this wave for one b; 8 shfl total
    {
      int a0 = __shfl(p0, lrow, 64);
      int a1 = __shfl(p0, lrow + 16, 64);
      int a2 = __shfl(p0, lrow + 32, 64);
      int a3 = __shfl(p0, lrow + 48, 64);
      int b0 = __shfl(p1, lrow, 64);
      int b1 = __shfl(p1, lrow + 16, 64);
      int b2 = __shfl(p1, lrow + 32, 64);
      int b3 = __shfl(p1, lrow + 48, 64);
      if (lk == 0) {
        short* hnx = hx + (size_t)(t + 1) * 32768 + bid * 512 + wave * 4;
        u64 pk0 = (u64)(unsigned)((a0 & 0xffff) | (a1 << 16)) |
                  ((u64)(unsigned)((a2 & 0xffff) | (a3 << 16)) << 32);
        u64 pk1 = (u64)(unsigned)((b0 & 0xffff) | (b1 << 16)) |
                  ((u64)(unsigned)((b2 & 0xffff) | (b3 << 16)) << 32);
        __hip_atomic_store((u64*)(hnx + lrow * 16), pk0, __ATOMIC_RELAXED,
                           __HIP_MEMORY_SCOPE_AGENT);
        __hip_atomic_store((u64*)(hnx + (lrow + 16) * 16), pk1, __ATOMIC_RELAXED,
                           __HIP_MEMORY_SCOPE_AGENT);
      }
    }

    if (t != 127) {
      __syncthreads();  // drains h stores (vmcnt(0) before s_barrier)
      if (tid == 0)
        __hip_atomic_store(arr + (bid << 6), (unsigned)(ebase + t + 1),
                           __ATOMIC_RELAXED, __HIP_MEMORY_SCOPE_AGENT);
    }
  }

  cst[lrow * 1024 + u] = creg0;
  cst[(lrow + 16) * 1024 + u] = creg1;
}

// ---------- launch ----------
extern "C" void kernel_launch(void* const* d_in, const int* in_sizes, int n_in,
                              void* d_out, int out_size, void* d_ws, size_t ws_size,
                              hipStream_t stream) {
  const float* x = (const float*)d_in[0];
  const float* h0 = (const float*)d_in[1];
  const float* c0 = (const float*)d_in[2];
  const float* W[4] = {(const float*)d_in[3], (const float*)d_in[6],
                       (const float*)d_in[9], (const float*)d_in[12]};
  const float* U[4] = {(const float*)d_in[4], (const float*)d_in[7],
                       (const float*)d_in[10], (const float*)d_in[13]};
  const float* bv[4] = {(const float*)d_in[5], (const float*)d_in[8],
                        (const float*)d_in[11], (const float*)d_in[14]};
  const float* Wd1 = (const float*)d_in[15];
  const float* bd1 = (const float*)d_in[16];
  const float* Wd2 = (const float*)d_in[17];
  const float* bd2 = (const float*)d_in[18];
  float* out = (float*)d_out;

  float* ws = (float*)d_ws;
  float* xWp = ws;                               // 16,777,216 f (64MB)
  short* Utp = (short*)(ws + 16777216);          // 4,194,304 bf16
  short* Wtp = (short*)(ws + 18874368);          // 4,194,304 bf16
  short* xb = (short*)(ws + 20971520);           // 2,097,152 bf16
  short* hx = (short*)(ws + 22020096);           // 129*32768 bf16
  float* cst = ws + 24133632;                    // 32,768 f
  float* bp = ws + 24166400;                     // 16,384 f
  unsigned* arr = (unsigned*)(ws + 24182784);    // 4,096 u32 epoch slots
  short* D1 = (short*)xWp;                       // alias: xWp dead by dense head

  zero_cnt<<<16, 256, 0, stream>>>(arr);
  init2<<<128, 256, 0, stream>>>(h0, c0, hx, cst);
  cast_x<<<8192, 256, 0, stream>>>(x, xb);
  bias_perm<<<64, 256, 0, stream>>>(bv[0], bv[1], bv[2], bv[3], bp);

  for (int l = 0; l < 4; ++l) {
    const int K = (l == 0) ? 512 : 1024;
    transpose_cast<true><<<dim3(128, 32), 256, 0, stream>>>(U[l], Utp, 1024, 4096);
    transpose_cast<true><<<dim3(128, K / 32), 256, 0, stream>>>(W[l], Wtp, K, 4096);
    if (l == 0) {
      gemm_bf16<1, false><<<dim3(32, 32), 256, 0, stream>>>(
          xb, Wtp, bp, xWp, 4096, 4096, 512);
    } else {
      gemm_bf16<1, true><<<dim3(32, 32), 256, 0, stream>>>(
          hx + 32768, Wtp, bp + l * 4096, xWp, 4096, 4096, 1024);
      copy_h<<<64, 256, 0, stream>>>((const int*)(hx + 128 * 32768), (int*)hx);
    }
    lstm_persist<<<PBLK, 256, 0, stream>>>(xWp, Utp, hx, cst, arr, l * 128);
  }

  // dense head: A = layer-4 h sequence in hx layout
  transpose_cast<false><<<dim3(32, 32), 256, 0, stream>>>(Wd1, Wtp, 1024, 1024);
  gemm_bf16<2, true><<<dim3(8, 32), 256, 0, stream>>>(hx + 32768, Wtp, bd1, D1,
                                                      4096, 1024, 1024);
  transpose_cast<false><<<dim3(16, 32), 256, 0, stream>>>(Wd2, Wtp, 1024, 512);
  gemm_bf16<3, false><<<dim3(4, 32), 256, 0, stream>>>(D1, Wtp, bd2, out, 4096,
                                                       512, 1024);

  finalize2<<<128, 256, 0, stream>>>(hx + 128 * 32768, cst, out + 2097152);
}